// Round 4
// baseline (519.810 us; speedup 1.0000x reference)
//
#include <hip/hip_runtime.h>

#define TOPK 32
#define EMB 64
#define NBLK 1024          // persistent blocks: exactly 4/CU on 256 CUs
#define NPG  7             // max nodes per 8-lane group (1024*32*7 >= N)
#define ROWS_SLICE 40000u  // 2.56 MB table slice (< 4MB per-XCD L2)
#define MAXS 8             // max slices supported

// =====================================================================
// k0: block-partial |max| over emb. 1024 partials, no atomics (deterministic).
// =====================================================================
__global__ __launch_bounds__(256) void absmax_partial_kernel(
    const float* __restrict__ emb, float* __restrict__ partial, int total4)
{
    const float4* src = (const float4*)emb;
    float m = 0.0f;
    for (int i = blockIdx.x * 256 + threadIdx.x; i < total4; i += gridDim.x * 256) {
        float4 v = src[i];
        m = fmaxf(m, fmaxf(fmaxf(fabsf(v.x), fabsf(v.y)),
                           fmaxf(fabsf(v.z), fabsf(v.w))));
    }
    __shared__ float red[256];
    red[threadIdx.x] = m;
    __syncthreads();
    for (int s = 128; s > 0; s >>= 1) {
        if (threadIdx.x < s) red[threadIdx.x] = fmaxf(red[threadIdx.x], red[threadIdx.x + s]);
        __syncthreads();
    }
    if (threadIdx.x == 0) partial[blockIdx.x] = red[0];
}

// =====================================================================
// k1: reduce partials -> quantize fp32 -> int8; also zero the sentinel row,
// store step, and RE-ZERO the soft-barrier counters (graph replays reuse ws).
// =====================================================================
__global__ __launch_bounds__(256) void quant_kernel(
    const float* __restrict__ emb, signed char* __restrict__ emb8,
    const float* __restrict__ partial, float* __restrict__ stepOut,
    int* __restrict__ barP, int n_nodes, int a_blocks)
{
    const int t = threadIdx.x;
    __shared__ float red[256];
    float m = fmaxf(fmaxf(partial[t], partial[t + 256]),
                    fmaxf(partial[t + 512], partial[t + 768]));
    red[t] = m;
    __syncthreads();
    for (int s = 128; s > 0; s >>= 1) {
        if (t < s) red[t] = fmaxf(red[t], red[t + s]);
        __syncthreads();
    }
    const float maxv = fmaxf(red[0], 1e-20f);
    const float inv_step = 127.0f / maxv;

    if ((int)blockIdx.x < a_blocks) {
        const int gid = blockIdx.x * 256 + t;              // 16 elems per thread
        const int total16 = n_nodes * (EMB / 16);
        if (gid < total16) {
            const float4* src = (const float4*)emb + (size_t)gid * 4;
            unsigned int w[4];
            #pragma unroll
            for (int p = 0; p < 4; ++p) {
                float4 v = src[p];
                int q0 = (int)__builtin_rintf(fminf(fmaxf(v.x * inv_step, -127.f), 127.f));
                int q1 = (int)__builtin_rintf(fminf(fmaxf(v.y * inv_step, -127.f), 127.f));
                int q2 = (int)__builtin_rintf(fminf(fmaxf(v.z * inv_step, -127.f), 127.f));
                int q3 = (int)__builtin_rintf(fminf(fmaxf(v.w * inv_step, -127.f), 127.f));
                w[p] = (unsigned int)(q0 & 0xff) | ((unsigned int)(q1 & 0xff) << 8) |
                       ((unsigned int)(q2 & 0xff) << 16) | ((unsigned int)(q3 & 0xff) << 24);
            }
            ((int4*)emb8)[gid] = make_int4((int)w[0], (int)w[1], (int)w[2], (int)w[3]);
        }
    } else {
        if (t < 4)
            ((int4*)(emb8 + (size_t)n_nodes * EMB))[t] = make_int4(0, 0, 0, 0);
        if (t == 0) stepOut[0] = maxv / 127.0f;
        if (t >= 8 && t < 8 + MAXS) barP[t - 8] = 0;       // soft-barrier reset
    }
}

// =====================================================================
// k2: persistent slice-phased gather with SOFT inter-slice barriers.
//  - 1024 blocks, 4/CU guaranteed by LDS (37.6KB) + launch_bounds(256,4).
//  - Block owns npb(<=196) nodes; 8-lane group owns up to NPG=7 of them.
//  - Bucket neighbors by 2.56MB slice (intra-wave counting sort, proven R3).
//  - Between slices: device-scope atomic arrive + BOUNDED spin. The barrier
//    carries no data -> timeout / stale counters / non-residency can only
//    cost time, never correctness. Counters zeroed by quant each iteration.
//  - Exact int32 accumulate, fixed order -> deterministic, proven numerics.
// =====================================================================
#define ACC8(A, rx, ry) do {                                \
    A[0] += (int)(signed char)((rx) & 0xff);                \
    A[1] += (int)(signed char)(((rx) >> 8) & 0xff);         \
    A[2] += (int)(signed char)(((rx) >> 16) & 0xff);        \
    A[3] += ((int)(rx)) >> 24;                              \
    A[4] += (int)(signed char)((ry) & 0xff);                \
    A[5] += (int)(signed char)(((ry) >> 8) & 0xff);         \
    A[6] += (int)(signed char)(((ry) >> 16) & 0xff);        \
    A[7] += ((int)(ry)) >> 24; } while (0)

__global__ __launch_bounds__(256, 4) void gather_q8_coop_kernel(
    const signed char* __restrict__ emb8,
    const float* __restrict__ wei,
    const int*   __restrict__ nei,
    const float* __restrict__ stepPtr,
    int*         __restrict__ barP,
    float*       __restrict__ out,
    int n_nodes, int npb, int nslices)
{
    __shared__ int s_cnt[32][NPG][MAXS + 1];   // 8.1 KB, group stride 63 (odd)
    __shared__ int s_lst[32][NPG][33];         // 29.6 KB, group stride 231 (odd)

    const int gl    = threadIdx.x >> 3;
    const int lane  = threadIdx.x & 7;
    const int nbase = blockIdx.x * npb;

    // ---- bucketing: block-local, intra-wave choreography (proven in R3) ----
    #pragma unroll
    for (int m = 0; m < NPG; ++m) {
        s_cnt[gl][m][lane] = 0;                // 8 lanes zero MAXS=8 counters
        const int loc = m * 32 + gl;
        const int n   = nbase + loc;
        if (loc < npb && n < n_nodes) {
            const long base = (long)n * TOPK;
            const int4   j4 = *(const int4*)(nei + base + lane * 4);
            const float4 w4 = *(const float4*)(wei + base + lane * 4);
            int jm[4];
            jm[0] = (w4.x != 0.0f) ? j4.x : -1;
            jm[1] = (w4.y != 0.0f) ? j4.y : -1;
            jm[2] = (w4.z != 0.0f) ? j4.z : -1;
            jm[3] = (w4.w != 0.0f) ? j4.w : -1;

            #pragma unroll
            for (int c = 0; c < 4; ++c)
                if (jm[c] >= 0)
                    atomicAdd(&s_cnt[gl][m][(unsigned)jm[c] / ROWS_SLICE], 1);

            if (lane == 0) {
                int run = 0;
                for (int s = 0; s < nslices; ++s) {
                    const int c = s_cnt[gl][m][s];
                    s_cnt[gl][m][s] = run;
                    run += c;
                }
            }
            #pragma unroll
            for (int c = 0; c < 4; ++c)
                if (jm[c] >= 0) {
                    const int pos = atomicAdd(&s_cnt[gl][m][(unsigned)jm[c] / ROWS_SLICE], 1);
                    s_lst[gl][m][pos] = jm[c] << 6;
                }
            // s_cnt[gl][m][s] = END offset of slice s; [nslices-1] = tot
        }
    }

    int acc[NPG][8];
    #pragma unroll
    for (int m = 0; m < NPG; ++m)
        #pragma unroll
        for (int e = 0; e < 8; ++e) acc[m][e] = 0;

    const signed char* ebase = emb8 + lane * 8;

    for (int s = 0; s < nslices; ++s) {
        if (s > 0) {
            // ---- soft grid barrier (performance hint only; no data dep) ----
            __syncthreads();
            if (threadIdx.x == 0) {
                __hip_atomic_fetch_add(&barP[s - 1], 1, __ATOMIC_RELAXED,
                                       __HIP_MEMORY_SCOPE_AGENT);
                int spins = 0;
                while (__hip_atomic_load(&barP[s - 1], __ATOMIC_RELAXED,
                                         __HIP_MEMORY_SCOPE_AGENT) < NBLK &&
                       ++spins < 2000) {
                    __builtin_amdgcn_s_sleep(2);
                }
            }
            __syncthreads();
        }
        #pragma unroll
        for (int m = 0; m < NPG; ++m) {
            int i = (s == 0) ? 0 : s_cnt[gl][m][s - 1];
            const int e = s_cnt[gl][m][s];
            for (; i + 4 <= e; i += 4) {           // 4-wide chunks for MLP
                const int o0 = s_lst[gl][m][i];
                const int o1 = s_lst[gl][m][i + 1];
                const int o2 = s_lst[gl][m][i + 2];
                const int o3 = s_lst[gl][m][i + 3];
                const uint2 r0 = *(const uint2*)(ebase + o0);
                const uint2 r1 = *(const uint2*)(ebase + o1);
                const uint2 r2 = *(const uint2*)(ebase + o2);
                const uint2 r3 = *(const uint2*)(ebase + o3);
                ACC8(acc[m], r0.x, r0.y);
                ACC8(acc[m], r1.x, r1.y);
                ACC8(acc[m], r2.x, r2.y);
                ACC8(acc[m], r3.x, r3.y);
            }
            for (; i < e; ++i) {
                const int o = s_lst[gl][m][i];
                const uint2 r = *(const uint2*)(ebase + o);
                ACC8(acc[m], r.x, r.y);
            }
        }
    }

    const float step = stepPtr[0];
    #pragma unroll
    for (int m = 0; m < NPG; ++m) {
        const int loc = m * 32 + gl;
        const int n   = nbase + loc;
        if (loc < npb && n < n_nodes) {
            const int tot = s_cnt[gl][m][nslices - 1];
            const float mlt = step / ((float)tot + 1e-12f);
            float4 o0, o1;
            o0.x = acc[m][0] * mlt; o0.y = acc[m][1] * mlt;
            o0.z = acc[m][2] * mlt; o0.w = acc[m][3] * mlt;
            o1.x = acc[m][4] * mlt; o1.y = acc[m][5] * mlt;
            o1.z = acc[m][6] * mlt; o1.w = acc[m][7] * mlt;
            float* op = out + (size_t)n * EMB + lane * 8;
            *(float4*)op       = o0;
            *(float4*)(op + 4) = o1;
        }
    }
}

// =====================================================================
// k2-fallback: R0's proven free-running gather (sentinel zero row).
// =====================================================================
__global__ __launch_bounds__(256) void gather_q8_kernel(
    const signed char* __restrict__ emb8,
    const float* __restrict__ wei,
    const int*   __restrict__ nei,
    const float* __restrict__ stepPtr,
    float*       __restrict__ out,
    int n_nodes)
{
    const int tid  = blockIdx.x * 256 + threadIdx.x;
    const int n    = tid >> 3;
    const int lane = tid & 7;
    if (n >= n_nodes) return;

    const float step = stepPtr[0];
    const long base = (long)n * TOPK;
    const int4   j4 = *(const int4*)(nei + base + lane * 4);
    const float4 w4 = *(const float4*)(wei + base + lane * 4);
    int jm[4];
    jm[0] = (w4.x != 0.0f) ? j4.x : n_nodes;
    jm[1] = (w4.y != 0.0f) ? j4.y : n_nodes;
    jm[2] = (w4.z != 0.0f) ? j4.z : n_nodes;
    jm[3] = (w4.w != 0.0f) ? j4.w : n_nodes;

    int acc[8] = {0, 0, 0, 0, 0, 0, 0, 0};
    int cnt = 0;

    #pragma unroll
    for (int t2 = 0; t2 < 4; ++t2) {
        int j[8];
        #pragma unroll
        for (int k = 0; k < 8; ++k)
            j[k] = __shfl(jm[k & 3], t2 * 2 + (k >> 2), 8);
        uint2 r[8];
        #pragma unroll
        for (int k = 0; k < 8; ++k)
            r[k] = *(const uint2*)(emb8 + (size_t)j[k] * EMB + lane * 8);
        #pragma unroll
        for (int k = 0; k < 8; ++k) {
            cnt += (j[k] != n_nodes) ? 1 : 0;
            ACC8(acc, r[k].x, r[k].y);
        }
    }

    const float mlt = step / ((float)cnt + 1e-12f);
    float4 o0, o1;
    o0.x = acc[0] * mlt; o0.y = acc[1] * mlt; o0.z = acc[2] * mlt; o0.w = acc[3] * mlt;
    o1.x = acc[4] * mlt; o1.y = acc[5] * mlt; o1.z = acc[6] * mlt; o1.w = acc[7] * mlt;
    float* op = out + (size_t)n * EMB + lane * 8;
    *(float4*)op       = o0;
    *(float4*)(op + 4) = o1;
}

// =====================================================================
// Fallback (tiny ws): verified R0 fp32 kernel
// =====================================================================
__global__ __launch_bounds__(256) void pprgo_f32_kernel(
    const float* __restrict__ emb,
    const float* __restrict__ wei,
    const int*   __restrict__ nei,
    float*       __restrict__ out,
    int n_nodes)
{
    const int tid   = blockIdx.x * blockDim.x + threadIdx.x;
    const int group = tid >> 4;
    const int lane  = tid & 15;
    if (group >= n_nodes) return;
    const long base = (long)group * TOPK;
    const float w0 = wei[base + lane];
    const float w1 = wei[base + 16 + lane];
    const int   i0 = nei[base + lane];
    const int   i1 = nei[base + 16 + lane];
    const float m0 = (w0 != 0.0f) ? 1.0f : 0.0f;
    const float m1 = (w1 != 0.0f) ? 1.0f : 0.0f;
    float4 acc = make_float4(0.f, 0.f, 0.f, 0.f);
    float  cnt = 0.0f;
    #pragma unroll 8
    for (int k = 0; k < 16; ++k) {
        const int   j0 = __shfl(i0, k, 16);
        const float a0 = __shfl(m0, k, 16);
        const float4 r0 = *(const float4*)(emb + (size_t)j0 * EMB + lane * 4);
        acc.x += a0*r0.x; acc.y += a0*r0.y; acc.z += a0*r0.z; acc.w += a0*r0.w; cnt += a0;
        const int   j1 = __shfl(i1, k, 16);
        const float a1 = __shfl(m1, k, 16);
        const float4 r1 = *(const float4*)(emb + (size_t)j1 * EMB + lane * 4);
        acc.x += a1*r1.x; acc.y += a1*r1.y; acc.z += a1*r1.z; acc.w += a1*r1.w; cnt += a1;
    }
    const float sc = 1.0f / (cnt + 1e-12f);
    float4 o;
    o.x = acc.x*sc; o.y = acc.y*sc; o.z = acc.z*sc; o.w = acc.w*sc;
    *(float4*)(out + (size_t)group * EMB + lane * 4) = o;
}

extern "C" void kernel_launch(void* const* d_in, const int* in_sizes, int n_in,
                              void* d_out, int out_size, void* d_ws, size_t ws_size,
                              hipStream_t stream) {
    const float* emb = (const float*)d_in[0];   // [N, 64] fp32
    const float* wei = (const float*)d_in[1];   // [N, 32] fp32
    const int*   nei = (const int*)d_in[2];     // [N, 32] int32
    float*       out = (float*)d_out;           // [N, 1, 64] fp32

    const int n_nodes = in_sizes[1] / TOPK;     // 200000

    const size_t emb8_bytes  = (size_t)(n_nodes + 1) * EMB;            // 12.8MB + 64B
    const size_t partial_off = (emb8_bytes + 15) & ~(size_t)15;
    const size_t bar_off     = partial_off + 1024 * sizeof(float) + 16;
    const size_t need_q8     = bar_off + MAXS * sizeof(int) + 16;

    if (ws_size >= need_q8) {
        signed char* emb8    = (signed char*)d_ws;
        float*       partial = (float*)((char*)d_ws + partial_off);
        float*       stepP   = partial + 1024;
        int*         barP    = (int*)((char*)d_ws + bar_off);

        const int total4 = n_nodes * EMB / 4;
        absmax_partial_kernel<<<1024, 256, 0, stream>>>(emb, partial, total4);

        const int a_blocks = (n_nodes * (EMB / 16) + 255) / 256;       // 3125
        quant_kernel<<<a_blocks + 1, 256, 0, stream>>>(
            emb, emb8, partial, stepP, barP, n_nodes, a_blocks);

        const int npb     = (n_nodes + NBLK - 1) / NBLK;               // 196
        const int nslices = (int)((n_nodes + (int)ROWS_SLICE - 1) / (int)ROWS_SLICE); // 5
        if (npb <= NPG * 32 && nslices <= MAXS) {
            gather_q8_coop_kernel<<<NBLK, 256, 0, stream>>>(
                emb8, wei, nei, stepP, barP, out, n_nodes, npb, nslices);
        } else {
            const int g_blocks = (n_nodes * 8 + 255) / 256;
            gather_q8_kernel<<<g_blocks, 256, 0, stream>>>(
                emb8, wei, nei, stepP, out, n_nodes);
        }
    } else {
        const int threads = n_nodes * 16;
        pprgo_f32_kernel<<<(threads + 255) / 256, 256, 0, stream>>>(
            emb, wei, nei, out, n_nodes);
    }
}

// Round 5
// 473.723 us; speedup vs baseline: 1.0973x; 1.0973x over previous
//
#include <hip/hip_runtime.h>

#define TOPK 32
#define EMB 64
#define NBLK 1024          // persistent blocks: exactly 4/CU on 256 CUs
#define NPG  7             // max nodes per 8-lane group (1024*32*7 >= N)
#define ROWS_SLICE 40000u  // 2.56 MB table slice (< 4MB per-XCD L2)
#define MAXS 8             // max slices supported

typedef short s2v __attribute__((ext_vector_type(2)));

// =====================================================================
// k0: block-partial |max| over emb. 1024 partials, no atomics (deterministic).
// =====================================================================
__global__ __launch_bounds__(256) void absmax_partial_kernel(
    const float* __restrict__ emb, float* __restrict__ partial, int total4)
{
    const float4* src = (const float4*)emb;
    float m = 0.0f;
    for (int i = blockIdx.x * 256 + threadIdx.x; i < total4; i += gridDim.x * 256) {
        float4 v = src[i];
        m = fmaxf(m, fmaxf(fmaxf(fabsf(v.x), fabsf(v.y)),
                           fmaxf(fabsf(v.z), fabsf(v.w))));
    }
    __shared__ float red[256];
    red[threadIdx.x] = m;
    __syncthreads();
    for (int s = 128; s > 0; s >>= 1) {
        if (threadIdx.x < s) red[threadIdx.x] = fmaxf(red[threadIdx.x], red[threadIdx.x + s]);
        __syncthreads();
    }
    if (threadIdx.x == 0) partial[blockIdx.x] = red[0];
}

// =====================================================================
// k1: reduce partials -> quantize fp32 -> int8; zero sentinel row, store
// step, and RE-ZERO the soft-barrier counters (graph replays reuse ws).
// =====================================================================
__global__ __launch_bounds__(256) void quant_kernel(
    const float* __restrict__ emb, signed char* __restrict__ emb8,
    const float* __restrict__ partial, float* __restrict__ stepOut,
    int* __restrict__ barP, int n_nodes, int a_blocks)
{
    const int t = threadIdx.x;
    __shared__ float red[256];
    float m = fmaxf(fmaxf(partial[t], partial[t + 256]),
                    fmaxf(partial[t + 512], partial[t + 768]));
    red[t] = m;
    __syncthreads();
    for (int s = 128; s > 0; s >>= 1) {
        if (t < s) red[t] = fmaxf(red[t], red[t + s]);
        __syncthreads();
    }
    const float maxv = fmaxf(red[0], 1e-20f);
    const float inv_step = 127.0f / maxv;

    if ((int)blockIdx.x < a_blocks) {
        const int gid = blockIdx.x * 256 + t;              // 16 elems per thread
        const int total16 = n_nodes * (EMB / 16);
        if (gid < total16) {
            const float4* src = (const float4*)emb + (size_t)gid * 4;
            unsigned int w[4];
            #pragma unroll
            for (int p = 0; p < 4; ++p) {
                float4 v = src[p];
                int q0 = (int)__builtin_rintf(fminf(fmaxf(v.x * inv_step, -127.f), 127.f));
                int q1 = (int)__builtin_rintf(fminf(fmaxf(v.y * inv_step, -127.f), 127.f));
                int q2 = (int)__builtin_rintf(fminf(fmaxf(v.z * inv_step, -127.f), 127.f));
                int q3 = (int)__builtin_rintf(fminf(fmaxf(v.w * inv_step, -127.f), 127.f));
                w[p] = (unsigned int)(q0 & 0xff) | ((unsigned int)(q1 & 0xff) << 8) |
                       ((unsigned int)(q2 & 0xff) << 16) | ((unsigned int)(q3 & 0xff) << 24);
            }
            ((int4*)emb8)[gid] = make_int4((int)w[0], (int)w[1], (int)w[2], (int)w[3]);
        }
    } else {
        if (t < 4)
            ((int4*)(emb8 + (size_t)n_nodes * EMB))[t] = make_int4(0, 0, 0, 0);
        if (t == 0) stepOut[0] = maxv / 127.0f;
        if (t >= 8 && t < 8 + MAXS) barP[t - 8] = 0;       // soft-barrier reset
    }
}

// =====================================================================
// k2: persistent slice-phased gather, PACKED-i16 accumulators.
//  - Structure proven in R4 (FETCH 278->133MB) — only its resource profile
//    was broken (spill). Packed acc: 7 nodes x 8 dims = 28 VGPRs (was 56).
//    Sums bounded by 32*127=4064 < 32767 -> i16 exact, numerics unchanged.
//  - waves_per_eu(4,4): EXACT occupancy target. R4 showed min-only bounds
//    let the allocator target 8 waves/EU (64 VGPR) and spill; LDS caps us
//    at 4 blocks/CU anyway, so 4 waves/EU (<=128 VGPR) is free headroom.
//  - Soft barrier: performance hint only, no data crosses it; s_sleep(1),
//    cap 1500 (~40us worst case). Counters re-zeroed by quant each iter.
// =====================================================================
#define ACC8P(A, rx, ry) do {                                          \
    unsigned _p0 = __builtin_amdgcn_perm(0u, (rx), 0x010C000Cu);       \
    unsigned _p1 = __builtin_amdgcn_perm(0u, (rx), 0x030C020Cu);       \
    unsigned _p2 = __builtin_amdgcn_perm(0u, (ry), 0x010C000Cu);       \
    unsigned _p3 = __builtin_amdgcn_perm(0u, (ry), 0x030C020Cu);       \
    s2v _v0 = *(s2v*)&_p0, _v1 = *(s2v*)&_p1;                          \
    s2v _v2 = *(s2v*)&_p2, _v3 = *(s2v*)&_p3;                          \
    A[0] += (_v0 >> 8); A[1] += (_v1 >> 8);                            \
    A[2] += (_v2 >> 8); A[3] += (_v3 >> 8); } while (0)

__global__ __launch_bounds__(256)
__attribute__((amdgpu_waves_per_eu(4, 4)))
void gather_q8_coop_kernel(
    const signed char* __restrict__ emb8,
    const float* __restrict__ wei,
    const int*   __restrict__ nei,
    const float* __restrict__ stepPtr,
    int*         __restrict__ barP,
    float*       __restrict__ out,
    int n_nodes, int npb, int nslices)
{
    __shared__ int s_cnt[32][NPG][MAXS + 1];   // 8.1 KB
    __shared__ int s_lst[32][NPG][33];         // 29.6 KB  (37.6KB total -> 4 blk/CU)

    const int gl    = threadIdx.x >> 3;
    const int lane  = threadIdx.x & 7;
    const int nbase = blockIdx.x * npb;

    // ---- bucketing: block-local, intra-wave choreography (proven R3/R4) ----
    #pragma unroll
    for (int m = 0; m < NPG; ++m) {
        s_cnt[gl][m][lane] = 0;                // 8 lanes zero 8 counters
        const int loc = m * 32 + gl;
        const int n   = nbase + loc;
        if (loc < npb && n < n_nodes) {
            const long base = (long)n * TOPK;
            const int4   j4 = *(const int4*)(nei + base + lane * 4);
            const float4 w4 = *(const float4*)(wei + base + lane * 4);
            int jm[4];
            jm[0] = (w4.x != 0.0f) ? j4.x : -1;
            jm[1] = (w4.y != 0.0f) ? j4.y : -1;
            jm[2] = (w4.z != 0.0f) ? j4.z : -1;
            jm[3] = (w4.w != 0.0f) ? j4.w : -1;

            #pragma unroll
            for (int c = 0; c < 4; ++c)
                if (jm[c] >= 0)
                    atomicAdd(&s_cnt[gl][m][(unsigned)jm[c] / ROWS_SLICE], 1);

            if (lane == 0) {
                int run = 0;
                for (int s = 0; s < nslices; ++s) {
                    const int c = s_cnt[gl][m][s];
                    s_cnt[gl][m][s] = run;
                    run += c;
                }
            }
            #pragma unroll
            for (int c = 0; c < 4; ++c)
                if (jm[c] >= 0) {
                    const int pos = atomicAdd(&s_cnt[gl][m][(unsigned)jm[c] / ROWS_SLICE], 1);
                    s_lst[gl][m][pos] = jm[c] << 6;
                }
            // s_cnt[gl][m][s] = END offset of slice s; [nslices-1] = tot
        }
    }

    s2v acc[NPG][4];
    #pragma unroll
    for (int m = 0; m < NPG; ++m)
        #pragma unroll
        for (int e = 0; e < 4; ++e) acc[m][e] = (s2v)0;

    const signed char* ebase = emb8 + lane * 8;

    for (int s = 0; s < nslices; ++s) {
        if (s > 0) {
            // ---- soft grid barrier (hint only; no data dependency) ----
            __syncthreads();
            if (threadIdx.x == 0) {
                __hip_atomic_fetch_add(&barP[s - 1], 1, __ATOMIC_RELAXED,
                                       __HIP_MEMORY_SCOPE_AGENT);
                int spins = 0;
                while (__hip_atomic_load(&barP[s - 1], __ATOMIC_RELAXED,
                                         __HIP_MEMORY_SCOPE_AGENT) < NBLK &&
                       ++spins < 1500) {
                    __builtin_amdgcn_s_sleep(1);
                }
            }
            __syncthreads();
        }
        #pragma unroll
        for (int m = 0; m < NPG; ++m) {
            int i = (s == 0) ? 0 : s_cnt[gl][m][s - 1];
            const int e = s_cnt[gl][m][s];
            for (; i + 4 <= e; i += 4) {           // 4-wide chunks for MLP
                const int o0 = s_lst[gl][m][i];
                const int o1 = s_lst[gl][m][i + 1];
                const int o2 = s_lst[gl][m][i + 2];
                const int o3 = s_lst[gl][m][i + 3];
                const uint2 r0 = *(const uint2*)(ebase + o0);
                const uint2 r1 = *(const uint2*)(ebase + o1);
                const uint2 r2 = *(const uint2*)(ebase + o2);
                const uint2 r3 = *(const uint2*)(ebase + o3);
                ACC8P(acc[m], r0.x, r0.y);
                ACC8P(acc[m], r1.x, r1.y);
                ACC8P(acc[m], r2.x, r2.y);
                ACC8P(acc[m], r3.x, r3.y);
            }
            for (; i < e; ++i) {
                const int o = s_lst[gl][m][i];
                const uint2 r = *(const uint2*)(ebase + o);
                ACC8P(acc[m], r.x, r.y);
            }
        }
    }

    const float step = stepPtr[0];
    #pragma unroll
    for (int m = 0; m < NPG; ++m) {
        const int loc = m * 32 + gl;
        const int n   = nbase + loc;
        if (loc < npb && n < n_nodes) {
            const int tot = s_cnt[gl][m][nslices - 1];
            const float mlt = step / ((float)tot + 1e-12f);
            float4 o0, o1;
            o0.x = (float)acc[m][0].x * mlt; o0.y = (float)acc[m][0].y * mlt;
            o0.z = (float)acc[m][1].x * mlt; o0.w = (float)acc[m][1].y * mlt;
            o1.x = (float)acc[m][2].x * mlt; o1.y = (float)acc[m][2].y * mlt;
            o1.z = (float)acc[m][3].x * mlt; o1.w = (float)acc[m][3].y * mlt;
            float* op = out + (size_t)n * EMB + lane * 8;
            *(float4*)op       = o0;
            *(float4*)(op + 4) = o1;
        }
    }
}

// =====================================================================
// k2-fallback: R0's proven free-running gather (sentinel zero row).
// =====================================================================
#define ACC8(A, rx, ry) do {                                \
    A[0] += (int)(signed char)((rx) & 0xff);                \
    A[1] += (int)(signed char)(((rx) >> 8) & 0xff);         \
    A[2] += (int)(signed char)(((rx) >> 16) & 0xff);        \
    A[3] += ((int)(rx)) >> 24;                              \
    A[4] += (int)(signed char)((ry) & 0xff);                \
    A[5] += (int)(signed char)(((ry) >> 8) & 0xff);         \
    A[6] += (int)(signed char)(((ry) >> 16) & 0xff);        \
    A[7] += ((int)(ry)) >> 24; } while (0)

__global__ __launch_bounds__(256) void gather_q8_kernel(
    const signed char* __restrict__ emb8,
    const float* __restrict__ wei,
    const int*   __restrict__ nei,
    const float* __restrict__ stepPtr,
    float*       __restrict__ out,
    int n_nodes)
{
    const int tid  = blockIdx.x * 256 + threadIdx.x;
    const int n    = tid >> 3;
    const int lane = tid & 7;
    if (n >= n_nodes) return;

    const float step = stepPtr[0];
    const long base = (long)n * TOPK;
    const int4   j4 = *(const int4*)(nei + base + lane * 4);
    const float4 w4 = *(const float4*)(wei + base + lane * 4);
    int jm[4];
    jm[0] = (w4.x != 0.0f) ? j4.x : n_nodes;
    jm[1] = (w4.y != 0.0f) ? j4.y : n_nodes;
    jm[2] = (w4.z != 0.0f) ? j4.z : n_nodes;
    jm[3] = (w4.w != 0.0f) ? j4.w : n_nodes;

    int acc[8] = {0, 0, 0, 0, 0, 0, 0, 0};
    int cnt = 0;

    #pragma unroll
    for (int t2 = 0; t2 < 4; ++t2) {
        int j[8];
        #pragma unroll
        for (int k = 0; k < 8; ++k)
            j[k] = __shfl(jm[k & 3], t2 * 2 + (k >> 2), 8);
        uint2 r[8];
        #pragma unroll
        for (int k = 0; k < 8; ++k)
            r[k] = *(const uint2*)(emb8 + (size_t)j[k] * EMB + lane * 8);
        #pragma unroll
        for (int k = 0; k < 8; ++k) {
            cnt += (j[k] != n_nodes) ? 1 : 0;
            ACC8(acc, r[k].x, r[k].y);
        }
    }

    const float mlt = step / ((float)cnt + 1e-12f);
    float4 o0, o1;
    o0.x = acc[0] * mlt; o0.y = acc[1] * mlt; o0.z = acc[2] * mlt; o0.w = acc[3] * mlt;
    o1.x = acc[4] * mlt; o1.y = acc[5] * mlt; o1.z = acc[6] * mlt; o1.w = acc[7] * mlt;
    float* op = out + (size_t)n * EMB + lane * 8;
    *(float4*)op       = o0;
    *(float4*)(op + 4) = o1;
}

// =====================================================================
// Fallback (tiny ws): verified R0 fp32 kernel
// =====================================================================
__global__ __launch_bounds__(256) void pprgo_f32_kernel(
    const float* __restrict__ emb,
    const float* __restrict__ wei,
    const int*   __restrict__ nei,
    float*       __restrict__ out,
    int n_nodes)
{
    const int tid   = blockIdx.x * blockDim.x + threadIdx.x;
    const int group = tid >> 4;
    const int lane  = tid & 15;
    if (group >= n_nodes) return;
    const long base = (long)group * TOPK;
    const float w0 = wei[base + lane];
    const float w1 = wei[base + 16 + lane];
    const int   i0 = nei[base + lane];
    const int   i1 = nei[base + 16 + lane];
    const float m0 = (w0 != 0.0f) ? 1.0f : 0.0f;
    const float m1 = (w1 != 0.0f) ? 1.0f : 0.0f;
    float4 acc = make_float4(0.f, 0.f, 0.f, 0.f);
    float  cnt = 0.0f;
    #pragma unroll 8
    for (int k = 0; k < 16; ++k) {
        const int   j0 = __shfl(i0, k, 16);
        const float a0 = __shfl(m0, k, 16);
        const float4 r0 = *(const float4*)(emb + (size_t)j0 * EMB + lane * 4);
        acc.x += a0*r0.x; acc.y += a0*r0.y; acc.z += a0*r0.z; acc.w += a0*r0.w; cnt += a0;
        const int   j1 = __shfl(i1, k, 16);
        const float a1 = __shfl(m1, k, 16);
        const float4 r1 = *(const float4*)(emb + (size_t)j1 * EMB + lane * 4);
        acc.x += a1*r1.x; acc.y += a1*r1.y; acc.z += a1*r1.z; acc.w += a1*r1.w; cnt += a1;
    }
    const float sc = 1.0f / (cnt + 1e-12f);
    float4 o;
    o.x = acc.x*sc; o.y = acc.y*sc; o.z = acc.z*sc; o.w = acc.w*sc;
    *(float4*)(out + (size_t)group * EMB + lane * 4) = o;
}

extern "C" void kernel_launch(void* const* d_in, const int* in_sizes, int n_in,
                              void* d_out, int out_size, void* d_ws, size_t ws_size,
                              hipStream_t stream) {
    const float* emb = (const float*)d_in[0];   // [N, 64] fp32
    const float* wei = (const float*)d_in[1];   // [N, 32] fp32
    const int*   nei = (const int*)d_in[2];     // [N, 32] int32
    float*       out = (float*)d_out;           // [N, 1, 64] fp32

    const int n_nodes = in_sizes[1] / TOPK;     // 200000

    const size_t emb8_bytes  = (size_t)(n_nodes + 1) * EMB;            // 12.8MB + 64B
    const size_t partial_off = (emb8_bytes + 15) & ~(size_t)15;
    const size_t bar_off     = partial_off + 1024 * sizeof(float) + 16;
    const size_t need_q8     = bar_off + MAXS * sizeof(int) + 16;

    if (ws_size >= need_q8) {
        signed char* emb8    = (signed char*)d_ws;
        float*       partial = (float*)((char*)d_ws + partial_off);
        float*       stepP   = partial + 1024;
        int*         barP    = (int*)((char*)d_ws + bar_off);

        const int total4 = n_nodes * EMB / 4;
        absmax_partial_kernel<<<1024, 256, 0, stream>>>(emb, partial, total4);

        const int a_blocks = (n_nodes * (EMB / 16) + 255) / 256;       // 3125
        quant_kernel<<<a_blocks + 1, 256, 0, stream>>>(
            emb, emb8, partial, stepP, barP, n_nodes, a_blocks);

        const int npb     = (n_nodes + NBLK - 1) / NBLK;               // 196
        const int nslices = (int)((n_nodes + (int)ROWS_SLICE - 1) / (int)ROWS_SLICE); // 5
        if (npb <= NPG * 32 && nslices <= MAXS) {
            gather_q8_coop_kernel<<<NBLK, 256, 0, stream>>>(
                emb8, wei, nei, stepP, barP, out, n_nodes, npb, nslices);
        } else {
            const int g_blocks = (n_nodes * 8 + 255) / 256;
            gather_q8_kernel<<<g_blocks, 256, 0, stream>>>(
                emb8, wei, nei, stepP, out, n_nodes);
        }
    } else {
        const int threads = n_nodes * 16;
        pprgo_f32_kernel<<<(threads + 255) / 256, 256, 0, stream>>>(
            emb, wei, nei, out, n_nodes);
    }
}

// Round 6
// 471.527 us; speedup vs baseline: 1.1024x; 1.0047x over previous
//
#include <hip/hip_runtime.h>

#define TOPK 32
#define EMB 64
#define NBLK 1024          // persistent blocks: 4/CU launched, 5/CU capacity
#define NPG  7             // max nodes per 8-lane group (1024*32*7 >= N)
#define ROWS_SLICE 40000u  // 2.56 MB table slice (< 4MB per-XCD L2)
#define MAXS 8             // max slices supported
#define LSTRIDE 225        // NPG*32+1: flat group stride, 225%32==1 -> conflict-free

typedef short s2v __attribute__((ext_vector_type(2)));

// =====================================================================
// k0: block-partial |max| over emb. 1024 partials, no atomics (deterministic).
// =====================================================================
__global__ __launch_bounds__(256) void absmax_partial_kernel(
    const float* __restrict__ emb, float* __restrict__ partial, int total4)
{
    const float4* src = (const float4*)emb;
    float m = 0.0f;
    for (int i = blockIdx.x * 256 + threadIdx.x; i < total4; i += gridDim.x * 256) {
        float4 v = src[i];
        m = fmaxf(m, fmaxf(fmaxf(fabsf(v.x), fabsf(v.y)),
                           fmaxf(fabsf(v.z), fabsf(v.w))));
    }
    __shared__ float red[256];
    red[threadIdx.x] = m;
    __syncthreads();
    for (int s = 128; s > 0; s >>= 1) {
        if (threadIdx.x < s) red[threadIdx.x] = fmaxf(red[threadIdx.x], red[threadIdx.x + s]);
        __syncthreads();
    }
    if (threadIdx.x == 0) partial[blockIdx.x] = red[0];
}

// =====================================================================
// k1: reduce partials -> quantize fp32 -> int8; zero sentinel row, store
// step, and RE-ZERO the soft-barrier counters (graph replays reuse ws).
// =====================================================================
__global__ __launch_bounds__(256) void quant_kernel(
    const float* __restrict__ emb, signed char* __restrict__ emb8,
    const float* __restrict__ partial, float* __restrict__ stepOut,
    int* __restrict__ barP, int n_nodes, int a_blocks)
{
    const int t = threadIdx.x;
    __shared__ float red[256];
    float m = fmaxf(fmaxf(partial[t], partial[t + 256]),
                    fmaxf(partial[t + 512], partial[t + 768]));
    red[t] = m;
    __syncthreads();
    for (int s = 128; s > 0; s >>= 1) {
        if (t < s) red[t] = fmaxf(red[t], red[t + s]);
        __syncthreads();
    }
    const float maxv = fmaxf(red[0], 1e-20f);
    const float inv_step = 127.0f / maxv;

    if ((int)blockIdx.x < a_blocks) {
        const int gid = blockIdx.x * 256 + t;              // 16 elems per thread
        const int total16 = n_nodes * (EMB / 16);
        if (gid < total16) {
            const float4* src = (const float4*)emb + (size_t)gid * 4;
            unsigned int w[4];
            #pragma unroll
            for (int p = 0; p < 4; ++p) {
                float4 v = src[p];
                int q0 = (int)__builtin_rintf(fminf(fmaxf(v.x * inv_step, -127.f), 127.f));
                int q1 = (int)__builtin_rintf(fminf(fmaxf(v.y * inv_step, -127.f), 127.f));
                int q2 = (int)__builtin_rintf(fminf(fmaxf(v.z * inv_step, -127.f), 127.f));
                int q3 = (int)__builtin_rintf(fminf(fmaxf(v.w * inv_step, -127.f), 127.f));
                w[p] = (unsigned int)(q0 & 0xff) | ((unsigned int)(q1 & 0xff) << 8) |
                       ((unsigned int)(q2 & 0xff) << 16) | ((unsigned int)(q3 & 0xff) << 24);
            }
            ((int4*)emb8)[gid] = make_int4((int)w[0], (int)w[1], (int)w[2], (int)w[3]);
        }
    } else {
        if (t < 4)
            ((int4*)(emb8 + (size_t)n_nodes * EMB))[t] = make_int4(0, 0, 0, 0);
        if (t == 0) stepOut[0] = maxv / 127.0f;
        if (t >= 8 && t < 8 + MAXS) barP[t - 8] = 0;       // soft-barrier reset
    }
}

// =====================================================================
// k2: persistent slice-phased gather. R5 proved locality (FETCH 311->78MB)
// but died on barrier timeouts: LDS 37.9KB made capacity == launch (4/CU),
// so one unevenly-dispatched block -> non-resident -> every barrier hit the
// spin cap. Fixes:
//  (a) LDS 29.8KB -> capacity 5 blocks/CU, launch 4/CU: +-1 dispatch skew
//      still fully resident; barriers complete in ~us.
//  (b) per-slice END offsets live in registers (e_end[m], slice s at lane s),
//      broadcast via __shfl -> s_cnt shrinks to [32][8], reused per m.
//  (c) s_lst flat, group stride 225 (225%32==1): conflict-free broadcast.
//  (d) spin: s_sleep(2), cap 320 (<=~35us insurance, expected ~us).
//  Soft barrier: NO data crosses it -> timeout affects time only, never
//  correctness. Counters re-zeroed by quant each iteration.
// =====================================================================
#define ACC8P(A, rx, ry) do {                                          \
    unsigned _p0 = __builtin_amdgcn_perm(0u, (rx), 0x010C000Cu);       \
    unsigned _p1 = __builtin_amdgcn_perm(0u, (rx), 0x030C020Cu);       \
    unsigned _p2 = __builtin_amdgcn_perm(0u, (ry), 0x010C000Cu);       \
    unsigned _p3 = __builtin_amdgcn_perm(0u, (ry), 0x030C020Cu);       \
    s2v _v0 = *(s2v*)&_p0, _v1 = *(s2v*)&_p1;                          \
    s2v _v2 = *(s2v*)&_p2, _v3 = *(s2v*)&_p3;                          \
    A[0] += (_v0 >> 8); A[1] += (_v1 >> 8);                            \
    A[2] += (_v2 >> 8); A[3] += (_v3 >> 8); } while (0)

__global__ __launch_bounds__(256)
__attribute__((amdgpu_waves_per_eu(4, 4)))
void gather_q8_coop_kernel(
    const signed char* __restrict__ emb8,
    const float* __restrict__ wei,
    const int*   __restrict__ nei,
    const float* __restrict__ stepPtr,
    int*         __restrict__ barP,
    float*       __restrict__ out,
    int n_nodes, int npb, int nslices)
{
    __shared__ int s_lst[32 * LSTRIDE];   // 28.8 KB
    __shared__ int s_cnt[32][8];          // 1.0 KB  -> total 29.8KB: 5 blk/CU cap

    const int gl    = threadIdx.x >> 3;
    const int lane  = threadIdx.x & 7;
    const int nbase = blockIdx.x * npb;
    const int nb    = gridDim.x;

    // ---- bucketing: per-m counting sort, counters reused across m ----
    int e_end[NPG];                       // slice-s END offset lives at lane s
    #pragma unroll
    for (int m = 0; m < NPG; ++m) {
        s_cnt[gl][lane] = 0;              // 8 lanes zero 8 counters (own wave)
        const int loc = m * 32 + gl;
        const int n   = nbase + loc;
        int jm[4] = {-1, -1, -1, -1};
        if (loc < npb && n < n_nodes) {
            const long base = (long)n * TOPK;
            const int4   j4 = *(const int4*)(nei + base + lane * 4);
            const float4 w4 = *(const float4*)(wei + base + lane * 4);
            jm[0] = (w4.x != 0.0f) ? j4.x : -1;
            jm[1] = (w4.y != 0.0f) ? j4.y : -1;
            jm[2] = (w4.z != 0.0f) ? j4.z : -1;
            jm[3] = (w4.w != 0.0f) ? j4.w : -1;
            #pragma unroll
            for (int c = 0; c < 4; ++c)
                if (jm[c] >= 0)
                    atomicAdd(&s_cnt[gl][(unsigned)jm[c] / ROWS_SLICE], 1);
        }
        if (lane == 0) {                  // exclusive prefix -> starts
            int run = 0;
            for (int s = 0; s < nslices; ++s) {
                const int c = s_cnt[gl][s];
                s_cnt[gl][s] = run;
                run += c;
            }
        }
        if (loc < npb && n < n_nodes) {
            #pragma unroll
            for (int c = 0; c < 4; ++c)
                if (jm[c] >= 0) {
                    const int pos = atomicAdd(&s_cnt[gl][(unsigned)jm[c] / ROWS_SLICE], 1);
                    s_lst[gl * LSTRIDE + m * 32 + pos] = jm[c] << 6;
                }
        }
        e_end[m] = s_cnt[gl][lane];       // cursor == END offset of slice `lane`
    }

    s2v acc[NPG][4];
    #pragma unroll
    for (int m = 0; m < NPG; ++m)
        #pragma unroll
        for (int e = 0; e < 4; ++e) acc[m][e] = (s2v)0;

    const signed char* ebase = emb8 + lane * 8;

    for (int s = 0; s < nslices; ++s) {
        if (s > 0) {
            // ---- soft grid barrier (hint only; no data dependency) ----
            __syncthreads();
            if (threadIdx.x == 0) {
                const int prev = __hip_atomic_fetch_add(
                    &barP[s - 1], 1, __ATOMIC_RELAXED, __HIP_MEMORY_SCOPE_AGENT);
                if (prev + 1 < nb) {
                    int spins = 0;
                    while (__hip_atomic_load(&barP[s - 1], __ATOMIC_RELAXED,
                                             __HIP_MEMORY_SCOPE_AGENT) < nb &&
                           ++spins < 320) {
                        __builtin_amdgcn_s_sleep(2);
                    }
                }
            }
            __syncthreads();
        }
        #pragma unroll
        for (int m = 0; m < NPG; ++m) {
            int i       = (s == 0) ? 0 : __shfl(e_end[m], s - 1, 8);
            const int e = __shfl(e_end[m], s, 8);
            const int lbase = gl * LSTRIDE + m * 32;
            for (; i + 4 <= e; i += 4) {           // 4-wide chunks for MLP
                const int o0 = s_lst[lbase + i];
                const int o1 = s_lst[lbase + i + 1];
                const int o2 = s_lst[lbase + i + 2];
                const int o3 = s_lst[lbase + i + 3];
                const uint2 r0 = *(const uint2*)(ebase + o0);
                const uint2 r1 = *(const uint2*)(ebase + o1);
                const uint2 r2 = *(const uint2*)(ebase + o2);
                const uint2 r3 = *(const uint2*)(ebase + o3);
                ACC8P(acc[m], r0.x, r0.y);
                ACC8P(acc[m], r1.x, r1.y);
                ACC8P(acc[m], r2.x, r2.y);
                ACC8P(acc[m], r3.x, r3.y);
            }
            for (; i < e; ++i) {
                const int o = s_lst[lbase + i];
                const uint2 r = *(const uint2*)(ebase + o);
                ACC8P(acc[m], r.x, r.y);
            }
        }
    }

    const float step = stepPtr[0];
    #pragma unroll
    for (int m = 0; m < NPG; ++m) {
        const int loc = m * 32 + gl;
        const int n   = nbase + loc;
        if (loc < npb && n < n_nodes) {
            const int tot = __shfl(e_end[m], nslices - 1, 8);
            const float mlt = step / ((float)tot + 1e-12f);
            float4 o0, o1;
            o0.x = (float)acc[m][0].x * mlt; o0.y = (float)acc[m][0].y * mlt;
            o0.z = (float)acc[m][1].x * mlt; o0.w = (float)acc[m][1].y * mlt;
            o1.x = (float)acc[m][2].x * mlt; o1.y = (float)acc[m][2].y * mlt;
            o1.z = (float)acc[m][3].x * mlt; o1.w = (float)acc[m][3].y * mlt;
            float* op = out + (size_t)n * EMB + lane * 8;
            *(float4*)op       = o0;
            *(float4*)(op + 4) = o1;
        }
    }
}

// =====================================================================
// k2-fallback: R0's proven free-running gather (sentinel zero row).
// =====================================================================
#define ACC8(A, rx, ry) do {                                \
    A[0] += (int)(signed char)((rx) & 0xff);                \
    A[1] += (int)(signed char)(((rx) >> 8) & 0xff);         \
    A[2] += (int)(signed char)(((rx) >> 16) & 0xff);        \
    A[3] += ((int)(rx)) >> 24;                              \
    A[4] += (int)(signed char)((ry) & 0xff);                \
    A[5] += (int)(signed char)(((ry) >> 8) & 0xff);         \
    A[6] += (int)(signed char)(((ry) >> 16) & 0xff);        \
    A[7] += ((int)(ry)) >> 24; } while (0)

__global__ __launch_bounds__(256) void gather_q8_kernel(
    const signed char* __restrict__ emb8,
    const float* __restrict__ wei,
    const int*   __restrict__ nei,
    const float* __restrict__ stepPtr,
    float*       __restrict__ out,
    int n_nodes)
{
    const int tid  = blockIdx.x * 256 + threadIdx.x;
    const int n    = tid >> 3;
    const int lane = tid & 7;
    if (n >= n_nodes) return;

    const float step = stepPtr[0];
    const long base = (long)n * TOPK;
    const int4   j4 = *(const int4*)(nei + base + lane * 4);
    const float4 w4 = *(const float4*)(wei + base + lane * 4);
    int jm[4];
    jm[0] = (w4.x != 0.0f) ? j4.x : n_nodes;
    jm[1] = (w4.y != 0.0f) ? j4.y : n_nodes;
    jm[2] = (w4.z != 0.0f) ? j4.z : n_nodes;
    jm[3] = (w4.w != 0.0f) ? j4.w : n_nodes;

    int acc[8] = {0, 0, 0, 0, 0, 0, 0, 0};
    int cnt = 0;

    #pragma unroll
    for (int t2 = 0; t2 < 4; ++t2) {
        int j[8];
        #pragma unroll
        for (int k = 0; k < 8; ++k)
            j[k] = __shfl(jm[k & 3], t2 * 2 + (k >> 2), 8);
        uint2 r[8];
        #pragma unroll
        for (int k = 0; k < 8; ++k)
            r[k] = *(const uint2*)(emb8 + (size_t)j[k] * EMB + lane * 8);
        #pragma unroll
        for (int k = 0; k < 8; ++k) {
            cnt += (j[k] != n_nodes) ? 1 : 0;
            ACC8(acc, r[k].x, r[k].y);
        }
    }

    const float mlt = step / ((float)cnt + 1e-12f);
    float4 o0, o1;
    o0.x = acc[0] * mlt; o0.y = acc[1] * mlt; o0.z = acc[2] * mlt; o0.w = acc[3] * mlt;
    o1.x = acc[4] * mlt; o1.y = acc[5] * mlt; o1.z = acc[6] * mlt; o1.w = acc[7] * mlt;
    float* op = out + (size_t)n * EMB + lane * 8;
    *(float4*)op       = o0;
    *(float4*)(op + 4) = o1;
}

// =====================================================================
// Fallback (tiny ws): verified R0 fp32 kernel
// =====================================================================
__global__ __launch_bounds__(256) void pprgo_f32_kernel(
    const float* __restrict__ emb,
    const float* __restrict__ wei,
    const int*   __restrict__ nei,
    float*       __restrict__ out,
    int n_nodes)
{
    const int tid   = blockIdx.x * blockDim.x + threadIdx.x;
    const int group = tid >> 4;
    const int lane  = tid & 15;
    if (group >= n_nodes) return;
    const long base = (long)group * TOPK;
    const float w0 = wei[base + lane];
    const float w1 = wei[base + 16 + lane];
    const int   i0 = nei[base + lane];
    const int   i1 = nei[base + 16 + lane];
    const float m0 = (w0 != 0.0f) ? 1.0f : 0.0f;
    const float m1 = (w1 != 0.0f) ? 1.0f : 0.0f;
    float4 acc = make_float4(0.f, 0.f, 0.f, 0.f);
    float  cnt = 0.0f;
    #pragma unroll 8
    for (int k = 0; k < 16; ++k) {
        const int   j0 = __shfl(i0, k, 16);
        const float a0 = __shfl(m0, k, 16);
        const float4 r0 = *(const float4*)(emb + (size_t)j0 * EMB + lane * 4);
        acc.x += a0*r0.x; acc.y += a0*r0.y; acc.z += a0*r0.z; acc.w += a0*r0.w; cnt += a0;
        const int   j1 = __shfl(i1, k, 16);
        const float a1 = __shfl(m1, k, 16);
        const float4 r1 = *(const float4*)(emb + (size_t)j1 * EMB + lane * 4);
        acc.x += a1*r1.x; acc.y += a1*r1.y; acc.z += a1*r1.z; acc.w += a1*r1.w; cnt += a1;
    }
    const float sc = 1.0f / (cnt + 1e-12f);
    float4 o;
    o.x = acc.x*sc; o.y = acc.y*sc; o.z = acc.z*sc; o.w = acc.w*sc;
    *(float4*)(out + (size_t)group * EMB + lane * 4) = o;
}

extern "C" void kernel_launch(void* const* d_in, const int* in_sizes, int n_in,
                              void* d_out, int out_size, void* d_ws, size_t ws_size,
                              hipStream_t stream) {
    const float* emb = (const float*)d_in[0];   // [N, 64] fp32
    const float* wei = (const float*)d_in[1];   // [N, 32] fp32
    const int*   nei = (const int*)d_in[2];     // [N, 32] int32
    float*       out = (float*)d_out;           // [N, 1, 64] fp32

    const int n_nodes = in_sizes[1] / TOPK;     // 200000

    const size_t emb8_bytes  = (size_t)(n_nodes + 1) * EMB;            // 12.8MB + 64B
    const size_t partial_off = (emb8_bytes + 15) & ~(size_t)15;
    const size_t bar_off     = partial_off + 1024 * sizeof(float) + 16;
    const size_t need_q8     = bar_off + MAXS * sizeof(int) + 16;

    if (ws_size >= need_q8) {
        signed char* emb8    = (signed char*)d_ws;
        float*       partial = (float*)((char*)d_ws + partial_off);
        float*       stepP   = partial + 1024;
        int*         barP    = (int*)((char*)d_ws + bar_off);

        const int total4 = n_nodes * EMB / 4;
        absmax_partial_kernel<<<1024, 256, 0, stream>>>(emb, partial, total4);

        const int a_blocks = (n_nodes * (EMB / 16) + 255) / 256;       // 3125
        quant_kernel<<<a_blocks + 1, 256, 0, stream>>>(
            emb, emb8, partial, stepP, barP, n_nodes, a_blocks);

        const int npb     = (n_nodes + NBLK - 1) / NBLK;               // 196
        const int nslices = (int)((n_nodes + (int)ROWS_SLICE - 1) / (int)ROWS_SLICE); // 5
        if (npb <= NPG * 32 && nslices <= MAXS) {
            gather_q8_coop_kernel<<<NBLK, 256, 0, stream>>>(
                emb8, wei, nei, stepP, barP, out, n_nodes, npb, nslices);
        } else {
            const int g_blocks = (n_nodes * 8 + 255) / 256;
            gather_q8_kernel<<<g_blocks, 256, 0, stream>>>(
                emb8, wei, nei, stepP, out, n_nodes);
        }
    } else {
        const int threads = n_nodes * 16;
        pprgo_f32_kernel<<<(threads + 255) / 256, 256, 0, stream>>>(
            emb, wei, nei, out, n_nodes);
    }
}